// Round 1
// baseline (2502.886 us; speedup 1.0000x reference)
//
#include <hip/hip_runtime.h>

#define N_IN   262144
#define N_OUT  393216
#define M_PAIRS 262144
#define KK     27
#define CIN    32
#define COUT   64
#define BN_EPS 1e-5f

#define BPK 256                                   // blocks per kernel-offset k
#define PAIRS_PER_BLOCK (M_PAIRS / BPK)           // 1024
#define CONV_BLOCK 256
#define WAVES_PER_BLOCK (CONV_BLOCK / 64)         // 4
#define PAIRS_PER_WAVE (PAIRS_PER_BLOCK / WAVES_PER_BLOCK) // 256

// Kernel 1: rulebook gather -> per-pair [1x32]x[32x64] -> scatter-add.
// One wave handles one pair at a time; lane == output channel.
__global__ __launch_bounds__(CONV_BLOCK) void conv_scatter(
    const float* __restrict__ data,      // [N_IN, CIN]
    const float* __restrict__ W,         // [K, CIN, COUT]
    const int*   __restrict__ in_idx,    // [K, M]
    const int*   __restrict__ out_idx,   // [K, M]
    float*       __restrict__ out)       // [N_OUT, COUT] (pre-zeroed)
{
    __shared__ float Wlds[CIN * COUT];   // 8 KB: W_k staged per block
    const int k   = blockIdx.x / BPK;
    const int blk = blockIdx.x % BPK;

    for (int i = threadIdx.x; i < CIN * COUT; i += CONV_BLOCK)
        Wlds[i] = W[k * CIN * COUT + i];
    __syncthreads();

    const int wave = threadIdx.x >> 6;
    const int lane = threadIdx.x & 63;
    const int base = k * M_PAIRS + blk * PAIRS_PER_BLOCK + wave * PAIRS_PER_WAVE;

    for (int p = 0; p < PAIRS_PER_WAVE; ++p) {
        const int in_i  = in_idx[base + p];
        const int out_i = out_idx[base + p];
        // lanes 0..31 fetch the 128B row; lanes 32..63 fetch duplicates (same cachelines)
        const float val = data[in_i * CIN + (lane & 31)];
        float acc = 0.0f;
        #pragma unroll
        for (int c = 0; c < CIN; ++c) {
            const float rowv = __shfl(val, c, 64);   // broadcast data row elem c
            acc = fmaf(rowv, Wlds[c * COUT + lane], acc);
        }
        atomicAdd(&out[out_i * COUT + lane], acc);
    }
}

// Kernel 2: per-channel sum & sumsq over all N_OUT rows.
__global__ __launch_bounds__(256) void bn_stats(
    const float* __restrict__ out, float* __restrict__ stats /* [128] */)
{
    const int tid    = blockIdx.x * 256 + threadIdx.x;
    const int stride = gridDim.x * 256;          // multiple of 64 -> fixed channel per thread
    float s = 0.0f, sq = 0.0f;
    const int total = N_OUT * COUT;
    for (int i = tid; i < total; i += stride) {
        const float x = out[i];
        s += x;
        sq += x * x;
    }
    __shared__ float ls[256], lsq[256];
    ls[threadIdx.x]  = s;
    lsq[threadIdx.x] = sq;
    __syncthreads();
    const int c = threadIdx.x;
    if (c < 64) {
        // threads c, c+64, c+128, c+192 all handled channel c
        const float ts = ls[c] + ls[c + 64] + ls[c + 128] + ls[c + 192];
        const float tq = lsq[c] + lsq[c + 64] + lsq[c + 128] + lsq[c + 192];
        atomicAdd(&stats[c], ts);
        atomicAdd(&stats[64 + c], tq);
    }
}

// Kernel 3: in-place normalize, float4 vectorized.
__global__ __launch_bounds__(256) void bn_norm(
    float* __restrict__ out, const float* __restrict__ stats,
    const float* __restrict__ gamma, const float* __restrict__ beta)
{
    __shared__ float scale[COUT], bias[COUT];
    if (threadIdx.x < COUT) {
        const int c = threadIdx.x;
        const float invN = 1.0f / (float)N_OUT;
        const float mean = stats[c] * invN;
        const float var  = stats[64 + c] * invN - mean * mean;
        const float inv  = rsqrtf(var + BN_EPS);
        const float g    = gamma[c];
        scale[c] = inv * g;
        bias[c]  = beta[c] - mean * inv * g;
    }
    __syncthreads();

    const int tid    = blockIdx.x * blockDim.x + threadIdx.x;
    const int stride = gridDim.x * blockDim.x;
    const int total4 = N_OUT * COUT / 4;
    float4* o4 = (float4*)out;
    for (int i = tid; i < total4; i += stride) {
        float4 v = o4[i];
        const int c0 = (i * 4) & 63;   // 4 consecutive channels
        v.x = v.x * scale[c0 + 0] + bias[c0 + 0];
        v.y = v.y * scale[c0 + 1] + bias[c0 + 1];
        v.z = v.z * scale[c0 + 2] + bias[c0 + 2];
        v.w = v.w * scale[c0 + 3] + bias[c0 + 3];
        o4[i] = v;
    }
}

extern "C" void kernel_launch(void* const* d_in, const int* in_sizes, int n_in,
                              void* d_out, int out_size, void* d_ws, size_t ws_size,
                              hipStream_t stream) {
    const float* data    = (const float*)d_in[0];
    const float* W       = (const float*)d_in[1];
    const float* gamma   = (const float*)d_in[2];
    const float* beta    = (const float*)d_in[3];
    const int*   in_idx  = (const int*)d_in[4];
    const int*   out_idx = (const int*)d_in[5];
    float* out   = (float*)d_out;
    float* stats = (float*)d_ws;

    // Re-zero accumulators every call (graph-capture-safe async memset).
    hipMemsetAsync(d_out, 0, (size_t)N_OUT * COUT * sizeof(float), stream);
    hipMemsetAsync(d_ws, 0, 128 * sizeof(float), stream);

    conv_scatter<<<KK * BPK, CONV_BLOCK, 0, stream>>>(data, W, in_idx, out_idx, out);
    bn_stats<<<1024, 256, 0, stream>>>(out, stats);
    bn_norm<<<2048, 256, 0, stream>>>(out, stats, gamma, beta);
}